// Round 1
// baseline (462.177 us; speedup 1.0000x reference)
//
#include <hip/hip_runtime.h>

#define CIN 256
#define COUT 128

// ---------------- preprocessing: build CSR by destination ----------------

__global__ void k_init(int* ecnt, int* cursor, int* counter, int n) {
    int i = blockIdx.x * blockDim.x + threadIdx.x;
    if (i < n) { ecnt[i] = 0; cursor[i] = 0; }
    if (i == 0) counter[0] = 0;
}

__global__ void k_count(const int* __restrict__ dst, int* __restrict__ ecnt, int e) {
    int i = blockIdx.x * blockDim.x + threadIdx.x;
    if (i < e) atomicAdd(&ecnt[dst[i]], 1);
}

// dinv = rsqrt(in_degree + 1 self loop); offset[v] = contiguous slot via atomic bump
__global__ void k_dinv_off(const int* __restrict__ ecnt, float* __restrict__ dinv,
                           int* __restrict__ offset, int* __restrict__ counter, int n) {
    int i = blockIdx.x * blockDim.x + threadIdx.x;
    if (i < n) {
        dinv[i] = rsqrtf((float)(ecnt[i] + 1));
        offset[i] = atomicAdd(counter, ecnt[i]);
    }
}

__global__ void k_place(const int* __restrict__ src, const int* __restrict__ dst,
                        const int* __restrict__ offset, int* __restrict__ cursor,
                        int* __restrict__ sorted_src, int e) {
    int i = blockIdx.x * blockDim.x + threadIdx.x;
    if (i < e) {
        int d = dst[i];
        int p = atomicAdd(&cursor[d], 1);
        sorted_src[offset[d] + p] = src[i];
    }
}

// ---------------- fp32 tiled GEMM: XW = X @ W  (N x 256) @ (256 x 128) ----------------
// BM=64, BN=128, BK=32, 256 threads, thread tile 4x8

__global__ __launch_bounds__(256) void k_gemm(const float* __restrict__ X,
                                              const float* __restrict__ W,
                                              float* __restrict__ XW, int n) {
    __shared__ float As[64][33];   // +1 pad
    __shared__ float Bs[32][128];
    const int tid = threadIdx.x;
    const int block_row = blockIdx.x * 64;
    const int tc = tid & 15;   // 0..15 -> 8 cols each
    const int tr = tid >> 4;   // 0..15 -> 4 rows each

    float acc[4][8];
#pragma unroll
    for (int i = 0; i < 4; i++)
#pragma unroll
        for (int j = 0; j < 8; j++) acc[i][j] = 0.f;

    for (int k0 = 0; k0 < CIN; k0 += 32) {
        // A tile: 64 rows x 32 k = 512 float4, 2 per thread
#pragma unroll
        for (int l = 0; l < 2; l++) {
            int idx = tid + l * 256;
            int r = idx >> 3;
            int kq = idx & 7;
            int grow = block_row + r;
            float4 v = make_float4(0.f, 0.f, 0.f, 0.f);
            if (grow < n) v = *(const float4*)&X[(size_t)grow * CIN + k0 + kq * 4];
            As[r][kq * 4 + 0] = v.x; As[r][kq * 4 + 1] = v.y;
            As[r][kq * 4 + 2] = v.z; As[r][kq * 4 + 3] = v.w;
        }
        // B tile: 32 k x 128 n = 1024 float4, 4 per thread
#pragma unroll
        for (int l = 0; l < 4; l++) {
            int idx = tid + l * 256;
            int kk = idx >> 5;
            int nq = idx & 31;
            float4 v = *(const float4*)&W[(size_t)(k0 + kk) * COUT + nq * 4];
            *(float4*)&Bs[kk][nq * 4] = v;
        }
        __syncthreads();
#pragma unroll
        for (int k = 0; k < 32; k++) {
            float a[4];
#pragma unroll
            for (int i = 0; i < 4; i++) a[i] = As[tr * 4 + i][k];
            float b[8];
            *(float4*)&b[0] = *(const float4*)&Bs[k][tc * 8];
            *(float4*)&b[4] = *(const float4*)&Bs[k][tc * 8 + 4];
#pragma unroll
            for (int i = 0; i < 4; i++)
#pragma unroll
                for (int j = 0; j < 8; j++) acc[i][j] += a[i] * b[j];
        }
        __syncthreads();
    }
#pragma unroll
    for (int i = 0; i < 4; i++) {
        int grow = block_row + tr * 4 + i;
        if (grow < n) {
            *(float4*)&XW[(size_t)grow * COUT + tc * 8] =
                make_float4(acc[i][0], acc[i][1], acc[i][2], acc[i][3]);
            *(float4*)&XW[(size_t)grow * COUT + tc * 8 + 4] =
                make_float4(acc[i][4], acc[i][5], acc[i][6], acc[i][7]);
        }
    }
}

// ---------------- aggregation: one wave per node, float2 per lane ----------------

__global__ __launch_bounds__(256) void k_agg(const float* __restrict__ XW,
                                             const float* __restrict__ dinv,
                                             const int* __restrict__ ecnt,
                                             const int* __restrict__ offset,
                                             const int* __restrict__ sorted_src,
                                             const float* __restrict__ bias,
                                             const float* __restrict__ alpha,
                                             float* __restrict__ out, int n) {
    const int wave = threadIdx.x >> 6;
    const int lane = threadIdx.x & 63;
    const int v = blockIdx.x * 4 + wave;
    if (v >= n) return;

    const float dv = dinv[v];
    float2 acc;
    {   // self loop: norm = dinv[v]^2
        float nrm = dv * dv;
        float2 xv = *(const float2*)&XW[(size_t)v * COUT + lane * 2];
        acc.x = xv.x * nrm;
        acc.y = xv.y * nrm;
    }
    const int beg = offset[v];
    const int cnt = ecnt[v];
    for (int e = 0; e < cnt; e++) {
        int s = sorted_src[beg + e];
        float nrm = dinv[s] * dv;
        float2 xs = *(const float2*)&XW[(size_t)s * COUT + lane * 2];
        acc.x += xs.x * nrm;
        acc.y += xs.y * nrm;
    }
    float2 bb = *(const float2*)&bias[lane * 2];
    float2 aa = *(const float2*)&alpha[lane * 2];
    float o0 = acc.x + bb.x;
    float o1 = acc.y + bb.y;
    o0 = o0 > 0.f ? o0 : aa.x * o0;
    o1 = o1 > 0.f ? o1 : aa.y * o1;
    *(float2*)&out[(size_t)v * COUT + lane * 2] = make_float2(o0, o1);
}

// ---------------- launch ----------------

extern "C" void kernel_launch(void* const* d_in, const int* in_sizes, int n_in,
                              void* d_out, int out_size, void* d_ws, size_t ws_size,
                              hipStream_t stream) {
    const float* x     = (const float*)d_in[0];
    const int*   edge  = (const int*)d_in[1];
    const float* W     = (const float*)d_in[2];
    const float* bias  = (const float*)d_in[3];
    const float* alpha = (const float*)d_in[4];
    float* out = (float*)d_out;

    const int n = in_sizes[0] / CIN;       // 100000
    const int e = in_sizes[1] / 2;         // 1600000
    const int* src = edge;
    const int* dst = edge + e;

    // workspace layout (bytes)
    char* ws = (char*)d_ws;
    float* xw        = (float*)ws;                                   // n*COUT floats
    float* dinv      = (float*)(ws + (size_t)n * COUT * 4);          // n floats
    int*   ecnt      = (int*)((char*)dinv + (size_t)n * 4);
    int*   cursor    = (int*)((char*)ecnt + (size_t)n * 4);
    int*   offset    = (int*)((char*)cursor + (size_t)n * 4);
    int*   sorted_src= (int*)((char*)offset + (size_t)n * 4);
    int*   counter   = (int*)((char*)sorted_src + (size_t)e * 4);

    const int TB = 256;
    k_init<<<(n + TB - 1) / TB, TB, 0, stream>>>(ecnt, cursor, counter, n);
    k_count<<<(e + TB - 1) / TB, TB, 0, stream>>>(dst, ecnt, e);
    k_dinv_off<<<(n + TB - 1) / TB, TB, 0, stream>>>(ecnt, dinv, offset, counter, n);
    k_place<<<(e + TB - 1) / TB, TB, 0, stream>>>(src, dst, offset, cursor, sorted_src, e);
    k_gemm<<<(n + 63) / 64, TB, 0, stream>>>(x, W, xw, n);
    k_agg<<<(n + 3) / 4, TB, 0, stream>>>(xw, dinv, ecnt, offset, sorted_src, bias, alpha, out, n);
}

// Round 2
// 363.856 us; speedup vs baseline: 1.2702x; 1.2702x over previous
//
#include <hip/hip_runtime.h>

#define CIN 256
#define COUT 128

// bf16 helpers (manual, RNE)
__device__ __forceinline__ unsigned f2bf(float x) {
    unsigned u = __float_as_uint(x);
    unsigned r = ((u >> 16) & 1u) + 0x7fffu;
    return (u + r) >> 16;
}
__device__ __forceinline__ float bflo(unsigned u) { return __uint_as_float(u << 16); }
__device__ __forceinline__ float bfhi(unsigned u) { return __uint_as_float(u & 0xffff0000u); }

// ---------------- preprocessing: build CSR by destination ----------------

__global__ void k_init(int* ecnt, int* cursor, int* counter, int n) {
    int i = blockIdx.x * blockDim.x + threadIdx.x;
    if (i < n) { ecnt[i] = 0; cursor[i] = 0; }
    if (i == 0) counter[0] = 0;
}

__global__ void k_count(const int* __restrict__ dst, int* __restrict__ ecnt, int e) {
    int i = blockIdx.x * blockDim.x + threadIdx.x;
    if (i < e) atomicAdd(&ecnt[dst[i]], 1);
}

__global__ void k_dinv_off(const int* __restrict__ ecnt, float* __restrict__ dinv,
                           int* __restrict__ offset, int* __restrict__ counter, int n) {
    int i = blockIdx.x * blockDim.x + threadIdx.x;
    if (i < n) {
        dinv[i] = rsqrtf((float)(ecnt[i] + 1));
        offset[i] = atomicAdd(counter, ecnt[i]);
    }
}

// place edges into CSR slots, fusing the edge norm (dinv[s]*dinv[d]) into the record
__global__ void k_place(const int* __restrict__ src, const int* __restrict__ dst,
                        const float* __restrict__ dinv,
                        const int* __restrict__ offset, int* __restrict__ cursor,
                        int2* __restrict__ edges, int e) {
    int i = blockIdx.x * blockDim.x + threadIdx.x;
    if (i < e) {
        int s = src[i];
        int d = dst[i];
        int p = atomicAdd(&cursor[d], 1);
        edges[offset[d] + p] = make_int2(s, __float_as_int(dinv[s] * dinv[d]));
    }
}

// ---------------- fp32 tiled GEMM: XW = X @ W, output stored bf16 ----------------
// BM=64, BN=128, BK=32, 256 threads, thread tile 4x8

__global__ __launch_bounds__(256) void k_gemm(const float* __restrict__ X,
                                              const float* __restrict__ W,
                                              unsigned* __restrict__ XWb, int n) {
    __shared__ float As[64][33];   // +1 pad
    __shared__ float Bs[32][128];
    const int tid = threadIdx.x;
    const int block_row = blockIdx.x * 64;
    const int tc = tid & 15;   // 0..15 -> 8 cols each
    const int tr = tid >> 4;   // 0..15 -> 4 rows each

    float acc[4][8];
#pragma unroll
    for (int i = 0; i < 4; i++)
#pragma unroll
        for (int j = 0; j < 8; j++) acc[i][j] = 0.f;

    for (int k0 = 0; k0 < CIN; k0 += 32) {
#pragma unroll
        for (int l = 0; l < 2; l++) {
            int idx = tid + l * 256;
            int r = idx >> 3;
            int kq = idx & 7;
            int grow = block_row + r;
            float4 v = make_float4(0.f, 0.f, 0.f, 0.f);
            if (grow < n) v = *(const float4*)&X[(size_t)grow * CIN + k0 + kq * 4];
            As[r][kq * 4 + 0] = v.x; As[r][kq * 4 + 1] = v.y;
            As[r][kq * 4 + 2] = v.z; As[r][kq * 4 + 3] = v.w;
        }
#pragma unroll
        for (int l = 0; l < 4; l++) {
            int idx = tid + l * 256;
            int kk = idx >> 5;
            int nq = idx & 31;
            float4 v = *(const float4*)&W[(size_t)(k0 + kk) * COUT + nq * 4];
            *(float4*)&Bs[kk][nq * 4] = v;
        }
        __syncthreads();
#pragma unroll
        for (int k = 0; k < 32; k++) {
            float a[4];
#pragma unroll
            for (int i = 0; i < 4; i++) a[i] = As[tr * 4 + i][k];
            float b[8];
            *(float4*)&b[0] = *(const float4*)&Bs[k][tc * 8];
            *(float4*)&b[4] = *(const float4*)&Bs[k][tc * 8 + 4];
#pragma unroll
            for (int i = 0; i < 4; i++)
#pragma unroll
                for (int j = 0; j < 8; j++) acc[i][j] += a[i] * b[j];
        }
        __syncthreads();
    }
#pragma unroll
    for (int i = 0; i < 4; i++) {
        int grow = block_row + tr * 4 + i;
        if (grow < n) {
            uint4 o;
            o.x = f2bf(acc[i][0]) | (f2bf(acc[i][1]) << 16);
            o.y = f2bf(acc[i][2]) | (f2bf(acc[i][3]) << 16);
            o.z = f2bf(acc[i][4]) | (f2bf(acc[i][5]) << 16);
            o.w = f2bf(acc[i][6]) | (f2bf(acc[i][7]) << 16);
            *(uint4*)&XWb[(size_t)grow * (COUT / 2) + tc * 4] = o;
        }
    }
}

// ---------------- aggregation: one wave per node, 2 bf16 ch/lane, unroll x4 ----------------

__global__ __launch_bounds__(256) void k_agg(const unsigned* __restrict__ XWb,
                                             const float* __restrict__ dinv,
                                             const int* __restrict__ ecnt,
                                             const int* __restrict__ offset,
                                             const int2* __restrict__ edges,
                                             const float* __restrict__ bias,
                                             const float* __restrict__ alpha,
                                             float* __restrict__ out, int n) {
    const int wave = threadIdx.x >> 6;
    const int lane = threadIdx.x & 63;
    const int v = blockIdx.x * 4 + wave;
    if (v >= n) return;

    const float dv = dinv[v];
    float ax, ay;
    {   // self loop: norm = dinv[v]^2
        float nrm = dv * dv;
        unsigned u = XWb[(size_t)v * 64 + lane];
        ax = nrm * bflo(u);
        ay = nrm * bfhi(u);
    }
    const int beg = offset[v];
    const int cnt = ecnt[v];
    int e = 0;
    for (; e + 4 <= cnt; e += 4) {
        int2 e0 = edges[beg + e + 0];
        int2 e1 = edges[beg + e + 1];
        int2 e2 = edges[beg + e + 2];
        int2 e3 = edges[beg + e + 3];
        unsigned u0 = XWb[(size_t)e0.x * 64 + lane];
        unsigned u1 = XWb[(size_t)e1.x * 64 + lane];
        unsigned u2 = XWb[(size_t)e2.x * 64 + lane];
        unsigned u3 = XWb[(size_t)e3.x * 64 + lane];
        float n0 = __int_as_float(e0.y);
        float n1 = __int_as_float(e1.y);
        float n2 = __int_as_float(e2.y);
        float n3 = __int_as_float(e3.y);
        ax += n0 * bflo(u0); ay += n0 * bfhi(u0);
        ax += n1 * bflo(u1); ay += n1 * bfhi(u1);
        ax += n2 * bflo(u2); ay += n2 * bfhi(u2);
        ax += n3 * bflo(u3); ay += n3 * bfhi(u3);
    }
    for (; e < cnt; e++) {
        int2 ee = edges[beg + e];
        unsigned u = XWb[(size_t)ee.x * 64 + lane];
        float nr = __int_as_float(ee.y);
        ax += nr * bflo(u); ay += nr * bfhi(u);
    }
    float2 bb = *(const float2*)&bias[lane * 2];
    float2 aa = *(const float2*)&alpha[lane * 2];
    float o0 = ax + bb.x;
    float o1 = ay + bb.y;
    o0 = o0 > 0.f ? o0 : aa.x * o0;
    o1 = o1 > 0.f ? o1 : aa.y * o1;
    *(float2*)&out[(size_t)v * COUT + lane * 2] = make_float2(o0, o1);
}

// ---------------- launch ----------------

extern "C" void kernel_launch(void* const* d_in, const int* in_sizes, int n_in,
                              void* d_out, int out_size, void* d_ws, size_t ws_size,
                              hipStream_t stream) {
    const float* x     = (const float*)d_in[0];
    const int*   edge  = (const int*)d_in[1];
    const float* W     = (const float*)d_in[2];
    const float* bias  = (const float*)d_in[3];
    const float* alpha = (const float*)d_in[4];
    float* out = (float*)d_out;

    const int n = in_sizes[0] / CIN;       // 100000
    const int e = in_sizes[1] / 2;         // 1600000
    const int* src = edge;
    const int* dst = edge + e;

    // workspace layout (bytes), all chunks 16B-aligned
    char* ws = (char*)d_ws;
    unsigned* xwb   = (unsigned*)ws;                                  // n*64 u32 (bf16 pairs) = 25.6 MB
    float* dinv     = (float*)(ws + (size_t)n * (COUT / 2) * 4);      // n f32
    int*   ecnt     = (int*)((char*)dinv + (size_t)n * 4);
    int*   cursor   = (int*)((char*)ecnt + (size_t)n * 4);
    int*   offset   = (int*)((char*)cursor + (size_t)n * 4);
    int2*  edges    = (int2*)((char*)offset + (size_t)n * 4);         // e*8 = 12.8 MB
    int*   counter  = (int*)((char*)edges + (size_t)e * 8);

    const int TB = 256;
    k_init<<<(n + TB - 1) / TB, TB, 0, stream>>>(ecnt, cursor, counter, n);
    k_count<<<(e + TB - 1) / TB, TB, 0, stream>>>(dst, ecnt, e);
    k_dinv_off<<<(n + TB - 1) / TB, TB, 0, stream>>>(ecnt, dinv, offset, counter, n);
    k_place<<<(e + TB - 1) / TB, TB, 0, stream>>>(src, dst, dinv, offset, cursor, edges, e);
    k_gemm<<<(n + 63) / 64, TB, 0, stream>>>(x, W, xwb, n);
    k_agg<<<(n + 3) / 4, TB, 0, stream>>>(xwb, dinv, ecnt, offset, edges, bias, alpha, out, n);
}

// Round 3
// 288.054 us; speedup vs baseline: 1.6045x; 1.2632x over previous
//
#include <hip/hip_runtime.h>

#define CIN 256
#define COUT 128

typedef __attribute__((ext_vector_type(8))) short short8;
typedef __attribute__((ext_vector_type(4))) float f32x4;

// bf16 helpers (manual, RNE)
__device__ __forceinline__ unsigned f2bf(float x) {
    unsigned u = __float_as_uint(x);
    unsigned r = ((u >> 16) & 1u) + 0x7fffu;
    return (u + r) >> 16;
}
__device__ __forceinline__ float bflo(unsigned u) { return __uint_as_float(u << 16); }
__device__ __forceinline__ float bfhi(unsigned u) { return __uint_as_float(u & 0xffff0000u); }

// ---------------- preprocessing: build CSR by destination ----------------

__global__ void k_init(int* ecnt, int* cursor, int* counter, int n) {
    int i = blockIdx.x * blockDim.x + threadIdx.x;
    if (i < n) { ecnt[i] = 0; cursor[i] = 0; }
    if (i == 0) counter[0] = 0;
}

__global__ void k_count(const int* __restrict__ dst, int* __restrict__ ecnt, int e) {
    int i = blockIdx.x * blockDim.x + threadIdx.x;
    if (i < e) atomicAdd(&ecnt[dst[i]], 1);
}

__global__ void k_dinv_off(const int* __restrict__ ecnt, float* __restrict__ dinv,
                           int* __restrict__ offset, int* __restrict__ counter, int n) {
    int i = blockIdx.x * blockDim.x + threadIdx.x;
    if (i < n) {
        dinv[i] = rsqrtf((float)(ecnt[i] + 1));
        offset[i] = atomicAdd(counter, ecnt[i]);
    }
}

// place edges into CSR slots, fusing the edge norm (dinv[s]*dinv[d]) into the record
__global__ void k_place(const int* __restrict__ src, const int* __restrict__ dst,
                        const float* __restrict__ dinv,
                        const int* __restrict__ offset, int* __restrict__ cursor,
                        int2* __restrict__ edges, int e) {
    int i = blockIdx.x * blockDim.x + threadIdx.x;
    if (i < e) {
        int s = src[i];
        int d = dst[i];
        int p = atomicAdd(&cursor[d], 1);
        edges[offset[d] + p] = make_int2(s, __float_as_int(dinv[s] * dinv[d]));
    }
}

// ---------------- W pre-pack into MFMA B-fragment order ----------------
// B frag for 16x16x32: lane l supplies B[k][n] with k = kt*32 + (l>>4)*8 + j, n = nt*16 + (l&15).
// Wp layout: [(kt*8+nt)*64 + lane] -> uint4 (8 bf16, j ascending).

__global__ __launch_bounds__(256) void k_packW(const float* __restrict__ W,
                                               uint4* __restrict__ Wp) {
    int t = blockIdx.x * 256 + threadIdx.x;   // 0..4095: (kt,nt,lane)
    int lane = t & 63;
    int nt = (t >> 6) & 7;
    int kt = t >> 9;
    int kbase = kt * 32 + (lane >> 4) * 8;
    int col = nt * 16 + (lane & 15);
    unsigned o[4];
#pragma unroll
    for (int jj = 0; jj < 4; jj++) {
        float a = W[(size_t)(kbase + 2 * jj) * COUT + col];
        float b = W[(size_t)(kbase + 2 * jj + 1) * COUT + col];
        o[jj] = f2bf(a) | (f2bf(b) << 16);
    }
    Wp[t] = make_uint4(o[0], o[1], o[2], o[3]);
}

// ---------------- MFMA GEMM: XW = X @ W, bf16 output ----------------
// 4 waves/block, 16 rows/wave, full COUT=128 per wave (8 n-tiles).
// A frags direct from global X (fp32 -> bf16 in-register); B frags from packed Wp (L2-hot).

__global__ __launch_bounds__(256) void k_gemm_mfma(const float* __restrict__ X,
                                                   const uint4* __restrict__ Wp,
                                                   unsigned short* __restrict__ XWb, int n) {
    const int wave = threadIdx.x >> 6;
    const int lane = threadIdx.x & 63;
    const int row0 = blockIdx.x * 64 + wave * 16;
    int arow = row0 + (lane & 15);
    if (arow >= n) arow = n - 1;            // clamp (stores are masked)
    const int kgrp = (lane >> 4) * 8;

    f32x4 acc[8];
#pragma unroll
    for (int i = 0; i < 8; i++) acc[i] = (f32x4)0.f;

    const float* xptr = X + (size_t)arow * CIN + kgrp;

    union U { unsigned u[4]; short8 s; };

#pragma unroll
    for (int kt = 0; kt < 8; kt++) {
        float4 a0 = *(const float4*)(xptr + kt * 32);
        float4 a1 = *(const float4*)(xptr + kt * 32 + 4);
        U au;
        au.u[0] = f2bf(a0.x) | (f2bf(a0.y) << 16);
        au.u[1] = f2bf(a0.z) | (f2bf(a0.w) << 16);
        au.u[2] = f2bf(a1.x) | (f2bf(a1.y) << 16);
        au.u[3] = f2bf(a1.z) | (f2bf(a1.w) << 16);
        short8 afrag = au.s;
#pragma unroll
        for (int nt = 0; nt < 8; nt++) {
            uint4 b = Wp[(kt * 8 + nt) * 64 + lane];
            U bu;
            bu.u[0] = b.x; bu.u[1] = b.y; bu.u[2] = b.z; bu.u[3] = b.w;
            acc[nt] = __builtin_amdgcn_mfma_f32_16x16x32_bf16(afrag, bu.s, acc[nt], 0, 0, 0);
        }
    }

    // C/D: col = lane&15, row = (lane>>4)*4 + reg  [verified mapping]
    const int r0 = (lane >> 4) * 4;
    const int c = lane & 15;
#pragma unroll
    for (int nt = 0; nt < 8; nt++) {
#pragma unroll
        for (int r = 0; r < 4; r++) {
            int row = row0 + r0 + r;
            if (row < n)
                XWb[(size_t)row * COUT + nt * 16 + c] = (unsigned short)f2bf(acc[nt][r]);
        }
    }
}

// ---------------- aggregation: one wave per node, 2 bf16 ch/lane, unroll x4 ----------------

__global__ __launch_bounds__(256) void k_agg(const unsigned* __restrict__ XWb,
                                             const float* __restrict__ dinv,
                                             const int* __restrict__ ecnt,
                                             const int* __restrict__ offset,
                                             const int2* __restrict__ edges,
                                             const float* __restrict__ bias,
                                             const float* __restrict__ alpha,
                                             float* __restrict__ out, int n) {
    const int wave = threadIdx.x >> 6;
    const int lane = threadIdx.x & 63;
    const int v = blockIdx.x * 4 + wave;
    if (v >= n) return;

    const float dv = dinv[v];
    float ax, ay;
    {
        float nrm = dv * dv;
        unsigned u = XWb[(size_t)v * 64 + lane];
        ax = nrm * bflo(u);
        ay = nrm * bfhi(u);
    }
    const int beg = offset[v];
    const int cnt = ecnt[v];
    int e = 0;
    for (; e + 4 <= cnt; e += 4) {
        int2 e0 = edges[beg + e + 0];
        int2 e1 = edges[beg + e + 1];
        int2 e2 = edges[beg + e + 2];
        int2 e3 = edges[beg + e + 3];
        unsigned u0 = XWb[(size_t)e0.x * 64 + lane];
        unsigned u1 = XWb[(size_t)e1.x * 64 + lane];
        unsigned u2 = XWb[(size_t)e2.x * 64 + lane];
        unsigned u3 = XWb[(size_t)e3.x * 64 + lane];
        float n0 = __int_as_float(e0.y);
        float n1 = __int_as_float(e1.y);
        float n2 = __int_as_float(e2.y);
        float n3 = __int_as_float(e3.y);
        ax += n0 * bflo(u0); ay += n0 * bfhi(u0);
        ax += n1 * bflo(u1); ay += n1 * bfhi(u1);
        ax += n2 * bflo(u2); ay += n2 * bfhi(u2);
        ax += n3 * bflo(u3); ay += n3 * bfhi(u3);
    }
    for (; e < cnt; e++) {
        int2 ee = edges[beg + e];
        unsigned u = XWb[(size_t)ee.x * 64 + lane];
        float nr = __int_as_float(ee.y);
        ax += nr * bflo(u); ay += nr * bfhi(u);
    }
    float2 bb = *(const float2*)&bias[lane * 2];
    float2 aa = *(const float2*)&alpha[lane * 2];
    float o0 = ax + bb.x;
    float o1 = ay + bb.y;
    o0 = o0 > 0.f ? o0 : aa.x * o0;
    o1 = o1 > 0.f ? o1 : aa.y * o1;
    *(float2*)&out[(size_t)v * COUT + lane * 2] = make_float2(o0, o1);
}

// ---------------- launch ----------------

extern "C" void kernel_launch(void* const* d_in, const int* in_sizes, int n_in,
                              void* d_out, int out_size, void* d_ws, size_t ws_size,
                              hipStream_t stream) {
    const float* x     = (const float*)d_in[0];
    const int*   edge  = (const int*)d_in[1];
    const float* W     = (const float*)d_in[2];
    const float* bias  = (const float*)d_in[3];
    const float* alpha = (const float*)d_in[4];
    float* out = (float*)d_out;

    const int n = in_sizes[0] / CIN;       // 100000
    const int e = in_sizes[1] / 2;         // 1600000
    const int* src = edge;
    const int* dst = edge + e;

    // workspace layout (bytes), chunks 16B-aligned
    char* ws = (char*)d_ws;
    unsigned* xwb   = (unsigned*)ws;                                  // n*64 u32 (bf16 pairs) = 25.6 MB
    float* dinv     = (float*)(ws + (size_t)n * (COUT / 2) * 4);      // n f32
    int*   ecnt     = (int*)((char*)dinv + (size_t)n * 4);
    int*   cursor   = (int*)((char*)ecnt + (size_t)n * 4);
    int*   offset   = (int*)((char*)cursor + (size_t)n * 4);
    int2*  edges    = (int2*)((char*)offset + (size_t)n * 4);         // e*8 = 12.8 MB
    int*   counter  = (int*)((char*)edges + (size_t)e * 8);
    uint4* wpack    = (uint4*)((char*)counter + 256);                 // 64 KB

    const int TB = 256;
    k_init<<<(n + TB - 1) / TB, TB, 0, stream>>>(ecnt, cursor, counter, n);
    k_count<<<(e + TB - 1) / TB, TB, 0, stream>>>(dst, ecnt, e);
    k_dinv_off<<<(n + TB - 1) / TB, TB, 0, stream>>>(ecnt, dinv, offset, counter, n);
    k_place<<<(e + TB - 1) / TB, TB, 0, stream>>>(src, dst, dinv, offset, cursor, edges, e);
    k_packW<<<16, TB, 0, stream>>>(W, wpack);
    k_gemm_mfma<<<(n + 63) / 64, TB, 0, stream>>>(x, wpack, (unsigned short*)xwb, n);
    k_agg<<<(n + 3) / 4, TB, 0, stream>>>(xwb, dinv, ecnt, offset, edges, bias, alpha, out, n);
}